// Round 12
// baseline (137.200 us; speedup 1.0000x reference)
//
#include <hip/hip_runtime.h>

#define IN_DIM 256
#define OUT_DIM 128
#define N_CLS 40

#define SLICE 20352    // nodes per LDS histogram slice (2 x 79.5 KB LDS)
#define NE_CH 40       // edge chunks

typedef __attribute__((ext_vector_type(8))) short short8;
typedef __attribute__((ext_vector_type(4))) float floatx4;

static __device__ __forceinline__ unsigned short f2bf(float f) {
    union { float f; unsigned u; } v; v.f = f;
    unsigned r = v.u + 0x7FFF + ((v.u >> 16) & 1);
    return (unsigned short)(r >> 16);
}

// packed f32x2 -> bf16x2 (RNE), one HW instruction
static __device__ __forceinline__ unsigned cvtpk(float lo, float hi) {
    unsigned r;
    asm("v_cvt_pk_bf16_f32 %0, %1, %2" : "=v"(r) : "v"(lo), "v"(hi));
    return r;
}

// ---------------------------------------------------------------------------
// Kernel 1: LDS-privatized histograms -> partial_out/partial_in [NE_CH][n],
// PLUS (merged) Wt transpose+bf16 in trailing blocks (also zeroes `done`).
// ---------------------------------------------------------------------------
__global__ __launch_bounds__(256) void hist_wconv_kernel(
    const int* __restrict__ src, const int* __restrict__ dst,
    int* __restrict__ partial_out, int* __restrict__ partial_in,
    const float* __restrict__ W, unsigned short* __restrict__ Wt,
    int* __restrict__ done, int ne, int n, int chunk, int nbh)
{
    __shared__ __align__(16) int lh_out[SLICE];
    __shared__ __align__(16) int lh_in[SLICE];

    const int tid = threadIdx.x;

    if (blockIdx.x >= (unsigned)nbh) {           // wconv part
        if (blockIdx.x == (unsigned)nbh && tid == 0) *done = 0;
        int t = (blockIdx.x - nbh) * 256 + tid;
        if (t < IN_DIM * OUT_DIM) {
            int k = t >> 7, c = t & 127;
            Wt[c * IN_DIM + k] = f2bf(W[t]);
        }
        return;
    }

    const int s = blockIdx.x / NE_CH;
    const int e = blockIdx.x % NE_CH;
    const int lo = s * SLICE;
    const int hi = min(lo + SLICE, n);

    for (int i = tid; i < SLICE; i += 256) { lh_out[i] = 0; lh_in[i] = 0; }
    __syncthreads();

    const int start = e * chunk;
    const int end = min(start + chunk, ne);
    const int cnt4 = (end - start) >> 2;
    const int4* s4 = (const int4*)(src + start);
    const int4* d4 = (const int4*)(dst + start);
    for (int k = tid; k < cnt4; k += 256) {
        int4 sv = s4[k];
        int4 dv = d4[k];
        unsigned q;
        q = (unsigned)(sv.x - lo); if (q < SLICE) atomicAdd(&lh_out[q], 1);
        q = (unsigned)(sv.y - lo); if (q < SLICE) atomicAdd(&lh_out[q], 1);
        q = (unsigned)(sv.z - lo); if (q < SLICE) atomicAdd(&lh_out[q], 1);
        q = (unsigned)(sv.w - lo); if (q < SLICE) atomicAdd(&lh_out[q], 1);
        q = (unsigned)(dv.x - lo); if (q < SLICE) atomicAdd(&lh_in[q], 1);
        q = (unsigned)(dv.y - lo); if (q < SLICE) atomicAdd(&lh_in[q], 1);
        q = (unsigned)(dv.z - lo); if (q < SLICE) atomicAdd(&lh_in[q], 1);
        q = (unsigned)(dv.w - lo); if (q < SLICE) atomicAdd(&lh_in[q], 1);
    }
    for (int t = start + (cnt4 << 2) + tid; t < end; t += 256) {
        unsigned q;
        q = (unsigned)(src[t] - lo); if (q < SLICE) atomicAdd(&lh_out[q], 1);
        q = (unsigned)(dst[t] - lo); if (q < SLICE) atomicAdd(&lh_in[q], 1);
    }
    __syncthreads();

    const int cnt = hi - lo;
    const int c4 = cnt >> 2;
    int4* po = (int4*)(partial_out + (size_t)e * n + lo);
    int4* pi = (int4*)(partial_in + (size_t)e * n + lo);
    for (int i = tid; i < c4; i += 256) {
        po[i] = ((const int4*)lh_out)[i];
        pi[i] = ((const int4*)lh_in)[i];
    }
    for (int i = (c4 << 2) + tid; i < cnt; i += 256) {
        partial_out[(size_t)e * n + lo + i] = lh_out[i];
        partial_in[(size_t)e * n + lo + i] = lh_in[i];
    }
}

// ---------------------------------------------------------------------------
// Kernel 2: reduce partials -> cnt_out; partial_in -> exclusive prefix along
// the chunk axis; block-local (1024-node) exclusive scan -> row_start + bsum;
// LAST block (atomic counter) scans bsum -> boffs.
// ---------------------------------------------------------------------------
__global__ __launch_bounds__(256) void reduce_scan_kernel(
    int* __restrict__ partial_out, int* __restrict__ partial_in,
    int* __restrict__ cnt_out, int* __restrict__ row_start,
    int* __restrict__ bsum, int* __restrict__ boffs,
    int* __restrict__ done, int n)
{
    __shared__ int wsum[4];
    __shared__ int is_last;
    const int tid = threadIdx.x;
    const int lane = tid & 63, wid = tid >> 6;
    const int base = blockIdx.x * 1024 + tid * 4;

    int4 run = make_int4(0, 0, 0, 0);

    if (base + 4 <= n) {
        int4 sum = make_int4(0, 0, 0, 0);
#pragma unroll
        for (int e = 0; e < NE_CH; e++) {
            int4 v = *(const int4*)(partial_out + (size_t)e * n + base);
            sum.x += v.x; sum.y += v.y; sum.z += v.z; sum.w += v.w;
        }
        *(int4*)(cnt_out + base) = sum;

#pragma unroll
        for (int e = 0; e < NE_CH; e++) {
            int* p = partial_in + (size_t)e * n + base;
            int4 v = *(const int4*)p;
            *(int4*)p = run;
            run.x += v.x; run.y += v.y; run.z += v.z; run.w += v.w;
        }
    } else if (base <= n) {
        int rr[4] = {0, 0, 0, 0};
#pragma unroll
        for (int j = 0; j < 4; j++) {
            int pos = base + j;
            if (pos < n) {
                int sum = 0, r = 0;
                for (int e = 0; e < NE_CH; e++) {
                    sum += partial_out[(size_t)e * n + pos];
                    int v = partial_in[(size_t)e * n + pos];
                    partial_in[(size_t)e * n + pos] = r;
                    r += v;
                }
                cnt_out[pos] = sum;
                rr[j] = r;
            }
        }
        run.x = rr[0]; run.y = rr[1]; run.z = rr[2]; run.w = rr[3];
    }

    const int s = run.x + run.y + run.z + run.w;
    const int e1 = run.x, e2 = run.x + run.y, e3 = run.x + run.y + run.z;

    int incl = s;
#pragma unroll
    for (int off = 1; off < 64; off <<= 1) {
        int q = __shfl_up(incl, (unsigned)off, 64);
        if (lane >= off) incl += q;
    }
    if (lane == 63) wsum[wid] = incl;
    __syncthreads();
    int woff = 0;
    for (int w = 0; w < wid; ++w) woff += wsum[w];
    const int texcl = woff + incl - s;

    if (base + 4 <= n) {
        int4 o = make_int4(texcl, texcl + e1, texcl + e2, texcl + e3);
        *(int4*)(row_start + base) = o;
    } else if (base <= n) {
        const int eo[4] = {0, e1, e2, e3};
#pragma unroll
        for (int j = 0; j < 4; j++) {
            int pos = base + j;
            if (pos <= n) row_start[pos] = texcl + eo[j];
        }
    }
    if (tid == 0) bsum[blockIdx.x] = wsum[0] + wsum[1] + wsum[2] + wsum[3];

    __threadfence();
    if (tid == 0) {
        int prev = atomicAdd(done, 1);
        is_last = (prev == (int)gridDim.x - 1) ? 1 : 0;
    }
    __syncthreads();
    if (is_last && tid < 64) {
        __threadfence();                 // acquire all blocks' bsum
        const int nb = (int)gridDim.x;
        int carry = 0;
        for (int c = 0; c < nb; c += 64) {
            int i = c + lane;
            int v = (i < nb) ? bsum[i] : 0;
            int inc2 = v;
#pragma unroll
            for (int off = 1; off < 64; off <<= 1) {
                int q = __shfl_up(inc2, (unsigned)off, 64);
                if (lane >= off) inc2 += q;
            }
            if (i < nb) boffs[i] = carry + inc2 - v;
            carry += __shfl(inc2, 63, 64);
        }
        if (lane == 0) boffs[nb] = carry;
    }
}

// ---------------------------------------------------------------------------
// Kernel 3 (FUSED): blocks [0, nbh) = scatter with LDS cursors;
// blocks [nbh, nbh+ngb) = gemm1 MFMA. ~80 KB smem union (2 blocks/CU).
// ---------------------------------------------------------------------------
__global__ __launch_bounds__(256) void scatter_gemm_kernel(
    const int* __restrict__ src, const int* __restrict__ dst,
    const int* __restrict__ row_start, const int* __restrict__ boffs,
    const int* __restrict__ prefix_in, int* __restrict__ csr_src,
    const int* __restrict__ nodes, const float* __restrict__ emb,
    const unsigned short* __restrict__ Wt, const int* __restrict__ cnt_out,
    unsigned short* __restrict__ h,
    int ne, int n, int chunk, int nbh)
{
    __shared__ __align__(16) char smem[SLICE * 4];   // ~80 KB union

    const int tid = threadIdx.x;

    if (blockIdx.x < (unsigned)nbh) {
        // ---------------- scatter role ----------------
        int* cur = (int*)smem;
        const int s = blockIdx.x / NE_CH;
        const int e = blockIdx.x % NE_CH;
        const int lo = s * SLICE;
        const int hi = min(lo + SLICE, n);
        const int cnt = hi - lo;

        const int c4 = cnt >> 2;
        for (int i = tid; i < c4; i += 256) {
            int idx4 = lo + i * 4;
            int4 rs = *(const int4*)(row_start + idx4);
            int4 pf = *(const int4*)(prefix_in + (size_t)e * n + idx4);
            const int bo = boffs[idx4 >> 10];
            rs.x += pf.x + bo; rs.y += pf.y + bo;
            rs.z += pf.z + bo; rs.w += pf.w + bo;
            ((int4*)cur)[i] = rs;
        }
        for (int i = (c4 << 2) + tid; i < cnt; i += 256) {
            int pos = lo + i;
            cur[i] = row_start[pos] + boffs[pos >> 10]
                   + prefix_in[(size_t)e * n + pos];
        }
        __syncthreads();

        const int start = e * chunk;
        const int end = min(start + chunk, ne);
        const int cnt4e = (end - start) >> 2;
        const int4* s4 = (const int4*)(src + start);
        const int4* d4 = (const int4*)(dst + start);
        for (int k = tid; k < cnt4e; k += 256) {
            int4 sv = s4[k];
            int4 dv = d4[k];
            unsigned q;
            q = (unsigned)(dv.x - lo); if (q < SLICE) csr_src[atomicAdd(&cur[q], 1)] = sv.x;
            q = (unsigned)(dv.y - lo); if (q < SLICE) csr_src[atomicAdd(&cur[q], 1)] = sv.y;
            q = (unsigned)(dv.z - lo); if (q < SLICE) csr_src[atomicAdd(&cur[q], 1)] = sv.z;
            q = (unsigned)(dv.w - lo); if (q < SLICE) csr_src[atomicAdd(&cur[q], 1)] = sv.w;
        }
        for (int t = start + (cnt4e << 2) + tid; t < end; t += 256) {
            unsigned q = (unsigned)(dst[t] - lo);
            if (q < SLICE) csr_src[atomicAdd(&cur[q], 1)] = src[t];
        }
        return;
    }

    // ---------------- gemm1 role ----------------
    unsigned short* A_lds = (unsigned short*)smem;              // 10240 B
    unsigned short* B_lds = (unsigned short*)(smem + 10240);    // 10240 B
    int*   snode  = (int*)(smem + 20480);                       // 512 B
    float* sscale = (float*)(smem + 20992);                     // 512 B

    const int m0 = (blockIdx.x - nbh) * 128;

    if (tid < 128) {
        int gr = m0 + tid;
        snode[tid]  = (gr < n) ? nodes[gr] : 0;
        sscale[tid] = (gr < n) ? rsqrtf(fmaxf((float)cnt_out[gr], 1.0f)) : 0.0f;
    }
    __syncthreads();

    const int arow = tid >> 1, aq = tid & 1;
    const float* aptr = emb + (size_t)snode[arow] * IN_DIM + aq * 16;
    const unsigned short* bptr = Wt + arow * IN_DIM + aq * 16;

    float    ar[16];
    unsigned bw[8];

#define LOAD_REGS(KK) do {                                           \
        _Pragma("unroll")                                            \
        for (int q = 0; q < 4; q++) {                                \
            const floatx4 v = *(const floatx4*)(aptr + (KK) * 32 + q * 4); \
            ar[q*4+0]=v[0]; ar[q*4+1]=v[1]; ar[q*4+2]=v[2]; ar[q*4+3]=v[3]; \
        }                                                            \
        const uint4 w0 = *(const uint4*)(bptr + (KK) * 32);          \
        const uint4 w1 = *(const uint4*)(bptr + (KK) * 32 + 8);      \
        bw[0]=w0.x; bw[1]=w0.y; bw[2]=w0.z; bw[3]=w0.w;              \
        bw[4]=w1.x; bw[5]=w1.y; bw[6]=w1.z; bw[7]=w1.w;              \
    } while (0)

#define WRITE_LDS() do {                                             \
        uint4 uv0, uv1;                                              \
        uv0.x = cvtpk(ar[0],  ar[1]);  uv0.y = cvtpk(ar[2],  ar[3]); \
        uv0.z = cvtpk(ar[4],  ar[5]);  uv0.w = cvtpk(ar[6],  ar[7]); \
        uv1.x = cvtpk(ar[8],  ar[9]);  uv1.y = cvtpk(ar[10], ar[11]);\
        uv1.z = cvtpk(ar[12], ar[13]); uv1.w = cvtpk(ar[14], ar[15]);\
        *(uint4*)&A_lds[arow * 40 + aq * 16]     = uv0;              \
        *(uint4*)&A_lds[arow * 40 + aq * 16 + 8] = uv1;              \
        uint4 b0, b1;                                                \
        b0.x=bw[0]; b0.y=bw[1]; b0.z=bw[2]; b0.w=bw[3];              \
        b1.x=bw[4]; b1.y=bw[5]; b1.z=bw[6]; b1.w=bw[7];              \
        *(uint4*)&B_lds[arow * 40 + aq * 16]     = b0;               \
        *(uint4*)&B_lds[arow * 40 + aq * 16 + 8] = b1;               \
    } while (0)

    const int wave = tid >> 6, lane = tid & 63;
    const int wr = (wave & 1) * 64;
    const int wc = (wave >> 1) * 64;
    const int fr = lane & 15;
    const int koff = (lane >> 4) * 8;

    floatx4 acc[4][4];
#pragma unroll
    for (int i = 0; i < 4; i++)
#pragma unroll
        for (int j = 0; j < 4; j++) acc[i][j] = (floatx4){0.f, 0.f, 0.f, 0.f};

    LOAD_REGS(0);
    WRITE_LDS();

    for (int kk = 0; kk < 8; ++kk) {
        if (kk < 7) LOAD_REGS(kk + 1);
        __syncthreads();
        short8 af[4], bf[4];
#pragma unroll
        for (int t = 0; t < 4; t++) {
            af[t] = *(const short8*)&A_lds[(wr + t * 16 + fr) * 40 + koff];
            bf[t] = *(const short8*)&B_lds[(wc + t * 16 + fr) * 40 + koff];
        }
#pragma unroll
        for (int rt = 0; rt < 4; rt++)
#pragma unroll
            for (int ct = 0; ct < 4; ct++)
                acc[rt][ct] = __builtin_amdgcn_mfma_f32_16x16x32_bf16(
                    bf[ct], af[rt], acc[rt][ct], 0, 0, 0);
        __syncthreads();
        if (kk < 7) WRITE_LDS();
    }

#pragma unroll
    for (int rt = 0; rt < 4; rt++) {
        int lrow = wr + rt * 16 + fr;
        int grow = m0 + lrow;
        float sc = sscale[lrow];
        if (grow < n) {
#pragma unroll
            for (int ct = 0; ct < 4; ct++) {
                int col = wc + ct * 16 + (lane >> 4) * 4;
                uint2 o;
                o.x = cvtpk(acc[rt][ct][0] * sc, acc[rt][ct][1] * sc);
                o.y = cvtpk(acc[rt][ct][2] * sc, acc[rt][ct][3] * sc);
                *(uint2*)&h[(size_t)grow * OUT_DIM + col] = o;
            }
        }
    }
#undef LOAD_REGS
#undef WRITE_LDS
}

// ---------------------------------------------------------------------------
// Kernel 4 (FUSED): CSR-SpMM + norm + bias + MFMA MLP.
// 512 thr (8 waves), 32 rows/block. Each wave gathers 4 rows (16 outstanding
// 256B h-loads), stores f32 feat to d_out AND bf16 feat to LDS [32][136].
// After barrier, waves 0-5 compute logits via 16x16x32 MFMA (2 rg x 3 ct).
// ---------------------------------------------------------------------------
__global__ __launch_bounds__(512) void spmm_mlp_kernel(
    const int* __restrict__ row_start, const int* __restrict__ boffs,
    const int* __restrict__ csr_src, const unsigned short* __restrict__ h,
    const float* __restrict__ bias, const float* __restrict__ mlp_w,
    const float* __restrict__ mlp_b,
    float* __restrict__ out_feat, float* __restrict__ out_logits, int n)
{
    __shared__ unsigned short s_fo[32][136];    // bf16 feats, pad-136
    __shared__ unsigned short s_w[48 * 136];    // mlp_w^T bf16, pad-136
    __shared__ float s_mlpb[48];

    const int tid = threadIdx.x;
    const int wave = tid >> 6, lane = tid & 63;
    const int m0 = blockIdx.x * 32;

    // stage mlp_w^T (used only after the barrier)
    for (int i = tid; i < 48 * 128; i += 512) {
        int cls = i >> 7, k = i & 127;
        s_w[cls * 136 + k] =
            (cls < N_CLS) ? f2bf(mlp_w[(size_t)k * N_CLS + cls]) : (unsigned short)0;
    }
    if (tid < 48) s_mlpb[tid] = (tid < N_CLS) ? mlp_b[tid] : 0.f;

    const int c2 = lane * 2;
    const float bi0 = bias[c2], bi1 = bias[c2 + 1];

    // ---------------- spmm phase: 4 rows per wave ----------------
#pragma unroll
    for (int r = 0; r < 4; r++) {
        const int lr = wave * 4 + r;       // 0..31
        const int row = m0 + lr;
        if (row < n) {
            const int rs = row_start[row]     + boffs[row >> 10];
            const int re = row_start[row + 1] + boffs[(row + 1) >> 10];
            const int deg = re - rs;

            float aL[4] = {0.f, 0.f, 0.f, 0.f};
            float aH[4] = {0.f, 0.f, 0.f, 0.f};

            for (int base = 0; base < deg; base += 64) {
                const int cnt = min(deg - base, 64);
                int idx = (lane < cnt) ? csr_src[rs + base + lane] : 0;
                int t = 0;
                for (; t + 15 < cnt; t += 16) {
                    int s[16];
#pragma unroll
                    for (int u = 0; u < 16; u++) s[u] = __shfl(idx, t + u, 64);
                    unsigned v[16];
#pragma unroll
                    for (int u = 0; u < 16; u++)
                        v[u] = *(const unsigned*)&h[(size_t)s[u] * OUT_DIM + c2];
#pragma unroll
                    for (int u = 0; u < 16; u++) {
                        union { unsigned uu; float f; } x, y;
                        x.uu = v[u] << 16;
                        y.uu = v[u] & 0xffff0000u;
                        aL[u & 3] += x.f;
                        aH[u & 3] += y.f;
                    }
                }
                for (; t + 3 < cnt; t += 4) {
                    int s[4];
#pragma unroll
                    for (int u = 0; u < 4; u++) s[u] = __shfl(idx, t + u, 64);
                    unsigned v[4];
#pragma unroll
                    for (int u = 0; u < 4; u++)
                        v[u] = *(const unsigned*)&h[(size_t)s[u] * OUT_DIM + c2];
#pragma unroll
                    for (int u = 0; u < 4; u++) {
                        union { unsigned uu; float f; } x, y;
                        x.uu = v[u] << 16;
                        y.uu = v[u] & 0xffff0000u;
                        aL[u] += x.f;
                        aH[u] += y.f;
                    }
                }
                for (; t < cnt; ++t) {
                    int s0 = __shfl(idx, t, 64);
                    unsigned v0 = *(const unsigned*)&h[(size_t)s0 * OUT_DIM + c2];
                    union { unsigned uu; float f; } x, y;
                    x.uu = v0 << 16;
                    y.uu = v0 & 0xffff0000u;
                    aL[0] += x.f;
                    aH[0] += y.f;
                }
            }

            const float nd = rsqrtf(fmaxf((float)deg, 1.0f));
            const float f0 = ((aL[0] + aL[1]) + (aL[2] + aL[3])) * nd + bi0;
            const float f1 = ((aH[0] + aH[1]) + (aH[2] + aH[3])) * nd + bi1;
            union { float f[2]; unsigned long long u; } o;
            o.f[0] = f0; o.f[1] = f1;
            __builtin_nontemporal_store(o.u,
                (unsigned long long*)&out_feat[(size_t)row * OUT_DIM + c2]);
            *(unsigned*)&s_fo[lr][c2] = cvtpk(f0, f1);
        } else {
            *(unsigned*)&s_fo[lr][c2] = 0u;
        }
    }
    __syncthreads();

    // ---------------- MLP MFMA phase: waves 0-5 ----------------
    if (wave < 6) {
        const int rg = wave / 3, ct = wave - rg * 3;
        const int r16 = lane & 15, koff = (lane >> 4) * 8;

        floatx4 acc = (floatx4){0.f, 0.f, 0.f, 0.f};
#pragma unroll
        for (int kk = 0; kk < 4; kk++) {
            short8 af = *(const short8*)&s_w[(ct * 16 + r16) * 136 + kk * 32 + koff];
            short8 bf = *(const short8*)&s_fo[rg * 16 + r16][kk * 32 + koff];
            acc = __builtin_amdgcn_mfma_f32_16x16x32_bf16(af, bf, acc, 0, 0, 0);
        }

        const int row = m0 + rg * 16 + r16;
        if (row < n) {
#pragma unroll
            for (int i = 0; i < 4; i++) {
                int cls = ct * 16 + (lane >> 4) * 4 + i;
                if (cls < N_CLS)
                    __builtin_nontemporal_store(acc[i] + s_mlpb[cls],
                        &out_logits[(size_t)row * N_CLS + cls]);
            }
        }
    }
}

// ---------------------------------------------------------------------------
extern "C" void kernel_launch(void* const* d_in, const int* in_sizes, int n_in,
                              void* d_out, int out_size, void* d_ws, size_t ws_size,
                              hipStream_t stream) {
    const int*   nodes = (const int*)d_in[0];
    const int*   src   = (const int*)d_in[1];
    const int*   dst   = (const int*)d_in[2];
    const float* emb   = (const float*)d_in[3];
    const float* W     = (const float*)d_in[4];
    const float* b     = (const float*)d_in[5];
    const float* mlp_w = (const float*)d_in[6];
    const float* mlp_b = (const float*)d_in[7];

    const int n  = in_sizes[0];   // 50000
    const int ne = in_sizes[1];   // 800000

    // ws layout (ints): cnt_out[n] | bsum[512] | boffs[512] | done[8] |
    //   row_start[n+8] | csr_src[ne] | partial_out[NE_CH*n] |
    //   partial_in[NE_CH*n] | bf16 Wt | bf16 h[n*128]
    int* cnt_out     = (int*)d_ws;
    int* bsum        = cnt_out + n;
    int* boffs       = bsum + 512;
    int* done        = boffs + 512;
    int* row_start   = done + 8;
    int* csr_src     = row_start + n + 8;
    int* partial_out = csr_src + ne;
    int* partial_in  = partial_out + (size_t)NE_CH * n;
    size_t off = ((size_t)(2 * n + 1048) + (size_t)ne + 2 * (size_t)NE_CH * n) * sizeof(int);
    off = (off + 15) & ~(size_t)15;
    unsigned short* Wt = (unsigned short*)((char*)d_ws + off);
    off += (size_t)IN_DIM * OUT_DIM * sizeof(unsigned short);
    off = (off + 15) & ~(size_t)15;
    unsigned short* h = (unsigned short*)((char*)d_ws + off);

    float* out_feat   = (float*)d_out;                    // n*128
    float* out_logits = out_feat + (size_t)n * OUT_DIM;   // n*40

    const int ns = (n + SLICE - 1) / SLICE;               // 3
    const int chunk = (((ne + NE_CH - 1) / NE_CH) + 3) & ~3;
    const int nbh = ns * NE_CH;                           // 120 hist blocks
    const int nbw = (IN_DIM * OUT_DIM + 255) / 256;       // 128 wconv blocks
    const int nb = (n + 1023) / 1024;                     // 49 scan blocks
    const int ngb = (n + 127) / 128;                      // 391 gemm blocks

    hist_wconv_kernel<<<nbh + nbw, 256, 0, stream>>>(
        src, dst, partial_out, partial_in, W, Wt, done, ne, n, chunk, nbh);
    reduce_scan_kernel<<<nb, 256, 0, stream>>>(
        partial_out, partial_in, cnt_out, row_start, bsum, boffs, done, n);
    scatter_gemm_kernel<<<nbh + ngb, 256, 0, stream>>>(
        src, dst, row_start, boffs, partial_in, csr_src,
        nodes, emb, Wt, cnt_out, h, ne, n, chunk, nbh);
    spmm_mlp_kernel<<<(n + 31) / 32, 512, 0, stream>>>(
        row_start, boffs, csr_src, h, b, mlp_w, mlp_b,
        out_feat, out_logits, n);
}

// Round 13
// 123.187 us; speedup vs baseline: 1.1137x; 1.1137x over previous
//
#include <hip/hip_runtime.h>

#define IN_DIM 256
#define OUT_DIM 128
#define N_CLS 40

#define SLICE 20352    // nodes per LDS histogram slice (2 x 79.5 KB LDS)
#define NE_CH 40       // edge chunks

typedef __attribute__((ext_vector_type(8))) short short8;
typedef __attribute__((ext_vector_type(4))) float floatx4;

static __device__ __forceinline__ unsigned short f2bf(float f) {
    union { float f; unsigned u; } v; v.f = f;
    unsigned r = v.u + 0x7FFF + ((v.u >> 16) & 1);
    return (unsigned short)(r >> 16);
}

// packed f32x2 -> bf16x2 (RNE), one HW instruction
static __device__ __forceinline__ unsigned cvtpk(float lo, float hi) {
    unsigned r;
    asm("v_cvt_pk_bf16_f32 %0, %1, %2" : "=v"(r) : "v"(lo), "v"(hi));
    return r;
}

// ---------------------------------------------------------------------------
// Kernel 1: LDS-privatized histograms -> partial_out/partial_in [NE_CH][n],
// PLUS (merged) Wt transpose+bf16 in trailing blocks (also zeroes `done`).
// ---------------------------------------------------------------------------
__global__ __launch_bounds__(256) void hist_wconv_kernel(
    const int* __restrict__ src, const int* __restrict__ dst,
    int* __restrict__ partial_out, int* __restrict__ partial_in,
    const float* __restrict__ W, unsigned short* __restrict__ Wt,
    int* __restrict__ done, int ne, int n, int chunk, int nbh)
{
    __shared__ __align__(16) int lh_out[SLICE];
    __shared__ __align__(16) int lh_in[SLICE];

    const int tid = threadIdx.x;

    if (blockIdx.x >= (unsigned)nbh) {           // wconv part
        if (blockIdx.x == (unsigned)nbh && tid == 0) *done = 0;
        int t = (blockIdx.x - nbh) * 256 + tid;
        if (t < IN_DIM * OUT_DIM) {
            int k = t >> 7, c = t & 127;
            Wt[c * IN_DIM + k] = f2bf(W[t]);
        }
        return;
    }

    const int s = blockIdx.x / NE_CH;
    const int e = blockIdx.x % NE_CH;
    const int lo = s * SLICE;
    const int hi = min(lo + SLICE, n);

    for (int i = tid; i < SLICE; i += 256) { lh_out[i] = 0; lh_in[i] = 0; }
    __syncthreads();

    const int start = e * chunk;
    const int end = min(start + chunk, ne);
    const int cnt4 = (end - start) >> 2;
    const int4* s4 = (const int4*)(src + start);
    const int4* d4 = (const int4*)(dst + start);
    for (int k = tid; k < cnt4; k += 256) {
        int4 sv = s4[k];
        int4 dv = d4[k];
        unsigned q;
        q = (unsigned)(sv.x - lo); if (q < SLICE) atomicAdd(&lh_out[q], 1);
        q = (unsigned)(sv.y - lo); if (q < SLICE) atomicAdd(&lh_out[q], 1);
        q = (unsigned)(sv.z - lo); if (q < SLICE) atomicAdd(&lh_out[q], 1);
        q = (unsigned)(sv.w - lo); if (q < SLICE) atomicAdd(&lh_out[q], 1);
        q = (unsigned)(dv.x - lo); if (q < SLICE) atomicAdd(&lh_in[q], 1);
        q = (unsigned)(dv.y - lo); if (q < SLICE) atomicAdd(&lh_in[q], 1);
        q = (unsigned)(dv.z - lo); if (q < SLICE) atomicAdd(&lh_in[q], 1);
        q = (unsigned)(dv.w - lo); if (q < SLICE) atomicAdd(&lh_in[q], 1);
    }
    for (int t = start + (cnt4 << 2) + tid; t < end; t += 256) {
        unsigned q;
        q = (unsigned)(src[t] - lo); if (q < SLICE) atomicAdd(&lh_out[q], 1);
        q = (unsigned)(dst[t] - lo); if (q < SLICE) atomicAdd(&lh_in[q], 1);
    }
    __syncthreads();

    const int cnt = hi - lo;
    const int c4 = cnt >> 2;
    int4* po = (int4*)(partial_out + (size_t)e * n + lo);
    int4* pi = (int4*)(partial_in + (size_t)e * n + lo);
    for (int i = tid; i < c4; i += 256) {
        po[i] = ((const int4*)lh_out)[i];
        pi[i] = ((const int4*)lh_in)[i];
    }
    for (int i = (c4 << 2) + tid; i < cnt; i += 256) {
        partial_out[(size_t)e * n + lo + i] = lh_out[i];
        partial_in[(size_t)e * n + lo + i] = lh_in[i];
    }
}

// ---------------------------------------------------------------------------
// Kernel 2: reduce partials -> cnt_out; partial_in -> exclusive prefix along
// the chunk axis; block-local (1024-node) exclusive scan -> row_start + bsum;
// LAST block (atomic counter) scans bsum -> boffs.
// ---------------------------------------------------------------------------
__global__ __launch_bounds__(256) void reduce_scan_kernel(
    int* __restrict__ partial_out, int* __restrict__ partial_in,
    int* __restrict__ cnt_out, int* __restrict__ row_start,
    int* __restrict__ bsum, int* __restrict__ boffs,
    int* __restrict__ done, int n)
{
    __shared__ int wsum[4];
    __shared__ int is_last;
    const int tid = threadIdx.x;
    const int lane = tid & 63, wid = tid >> 6;
    const int base = blockIdx.x * 1024 + tid * 4;

    int4 run = make_int4(0, 0, 0, 0);

    if (base + 4 <= n) {
        int4 sum = make_int4(0, 0, 0, 0);
#pragma unroll
        for (int e = 0; e < NE_CH; e++) {
            int4 v = *(const int4*)(partial_out + (size_t)e * n + base);
            sum.x += v.x; sum.y += v.y; sum.z += v.z; sum.w += v.w;
        }
        *(int4*)(cnt_out + base) = sum;

#pragma unroll
        for (int e = 0; e < NE_CH; e++) {
            int* p = partial_in + (size_t)e * n + base;
            int4 v = *(const int4*)p;
            *(int4*)p = run;
            run.x += v.x; run.y += v.y; run.z += v.z; run.w += v.w;
        }
    } else if (base <= n) {
        int rr[4] = {0, 0, 0, 0};
#pragma unroll
        for (int j = 0; j < 4; j++) {
            int pos = base + j;
            if (pos < n) {
                int sum = 0, r = 0;
                for (int e = 0; e < NE_CH; e++) {
                    sum += partial_out[(size_t)e * n + pos];
                    int v = partial_in[(size_t)e * n + pos];
                    partial_in[(size_t)e * n + pos] = r;
                    r += v;
                }
                cnt_out[pos] = sum;
                rr[j] = r;
            }
        }
        run.x = rr[0]; run.y = rr[1]; run.z = rr[2]; run.w = rr[3];
    }

    const int s = run.x + run.y + run.z + run.w;
    const int e1 = run.x, e2 = run.x + run.y, e3 = run.x + run.y + run.z;

    int incl = s;
#pragma unroll
    for (int off = 1; off < 64; off <<= 1) {
        int q = __shfl_up(incl, (unsigned)off, 64);
        if (lane >= off) incl += q;
    }
    if (lane == 63) wsum[wid] = incl;
    __syncthreads();
    int woff = 0;
    for (int w = 0; w < wid; ++w) woff += wsum[w];
    const int texcl = woff + incl - s;

    if (base + 4 <= n) {
        int4 o = make_int4(texcl, texcl + e1, texcl + e2, texcl + e3);
        *(int4*)(row_start + base) = o;
    } else if (base <= n) {
        const int eo[4] = {0, e1, e2, e3};
#pragma unroll
        for (int j = 0; j < 4; j++) {
            int pos = base + j;
            if (pos <= n) row_start[pos] = texcl + eo[j];
        }
    }
    if (tid == 0) bsum[blockIdx.x] = wsum[0] + wsum[1] + wsum[2] + wsum[3];

    __threadfence();
    if (tid == 0) {
        int prev = atomicAdd(done, 1);
        is_last = (prev == (int)gridDim.x - 1) ? 1 : 0;
    }
    __syncthreads();
    if (is_last && tid < 64) {
        __threadfence();                 // acquire all blocks' bsum
        const int nb = (int)gridDim.x;
        int carry = 0;
        for (int c = 0; c < nb; c += 64) {
            int i = c + lane;
            int v = (i < nb) ? bsum[i] : 0;
            int inc2 = v;
#pragma unroll
            for (int off = 1; off < 64; off <<= 1) {
                int q = __shfl_up(inc2, (unsigned)off, 64);
                if (lane >= off) inc2 += q;
            }
            if (i < nb) boffs[i] = carry + inc2 - v;
            carry += __shfl(inc2, 63, 64);
        }
        if (lane == 0) boffs[nb] = carry;
    }
}

// ---------------------------------------------------------------------------
// Kernel 3 (FUSED): blocks [0, nbh) = scatter with LDS cursors;
// blocks [nbh, nbh+ngb) = gemm1 MFMA. ~80 KB smem union (2 blocks/CU).
// ---------------------------------------------------------------------------
__global__ __launch_bounds__(256) void scatter_gemm_kernel(
    const int* __restrict__ src, const int* __restrict__ dst,
    const int* __restrict__ row_start, const int* __restrict__ boffs,
    const int* __restrict__ prefix_in, int* __restrict__ csr_src,
    const int* __restrict__ nodes, const float* __restrict__ emb,
    const unsigned short* __restrict__ Wt, const int* __restrict__ cnt_out,
    unsigned short* __restrict__ h,
    int ne, int n, int chunk, int nbh)
{
    __shared__ __align__(16) char smem[SLICE * 4];   // ~80 KB union

    const int tid = threadIdx.x;

    if (blockIdx.x < (unsigned)nbh) {
        // ---------------- scatter role ----------------
        int* cur = (int*)smem;
        const int s = blockIdx.x / NE_CH;
        const int e = blockIdx.x % NE_CH;
        const int lo = s * SLICE;
        const int hi = min(lo + SLICE, n);
        const int cnt = hi - lo;

        const int c4 = cnt >> 2;
        for (int i = tid; i < c4; i += 256) {
            int idx4 = lo + i * 4;
            int4 rs = *(const int4*)(row_start + idx4);
            int4 pf = *(const int4*)(prefix_in + (size_t)e * n + idx4);
            const int bo = boffs[idx4 >> 10];
            rs.x += pf.x + bo; rs.y += pf.y + bo;
            rs.z += pf.z + bo; rs.w += pf.w + bo;
            ((int4*)cur)[i] = rs;
        }
        for (int i = (c4 << 2) + tid; i < cnt; i += 256) {
            int pos = lo + i;
            cur[i] = row_start[pos] + boffs[pos >> 10]
                   + prefix_in[(size_t)e * n + pos];
        }
        __syncthreads();

        const int start = e * chunk;
        const int end = min(start + chunk, ne);
        const int cnt4e = (end - start) >> 2;
        const int4* s4 = (const int4*)(src + start);
        const int4* d4 = (const int4*)(dst + start);
        for (int k = tid; k < cnt4e; k += 256) {
            int4 sv = s4[k];
            int4 dv = d4[k];
            unsigned q;
            q = (unsigned)(dv.x - lo); if (q < SLICE) csr_src[atomicAdd(&cur[q], 1)] = sv.x;
            q = (unsigned)(dv.y - lo); if (q < SLICE) csr_src[atomicAdd(&cur[q], 1)] = sv.y;
            q = (unsigned)(dv.z - lo); if (q < SLICE) csr_src[atomicAdd(&cur[q], 1)] = sv.z;
            q = (unsigned)(dv.w - lo); if (q < SLICE) csr_src[atomicAdd(&cur[q], 1)] = sv.w;
        }
        for (int t = start + (cnt4e << 2) + tid; t < end; t += 256) {
            unsigned q = (unsigned)(dst[t] - lo);
            if (q < SLICE) csr_src[atomicAdd(&cur[q], 1)] = src[t];
        }
        return;
    }

    // ---------------- gemm1 role ----------------
    unsigned short* A_lds = (unsigned short*)smem;              // 10240 B
    unsigned short* B_lds = (unsigned short*)(smem + 10240);    // 10240 B
    int*   snode  = (int*)(smem + 20480);                       // 512 B
    float* sscale = (float*)(smem + 20992);                     // 512 B

    const int m0 = (blockIdx.x - nbh) * 128;

    if (tid < 128) {
        int gr = m0 + tid;
        snode[tid]  = (gr < n) ? nodes[gr] : 0;
        sscale[tid] = (gr < n) ? rsqrtf(fmaxf((float)cnt_out[gr], 1.0f)) : 0.0f;
    }
    __syncthreads();

    const int arow = tid >> 1, aq = tid & 1;
    const float* aptr = emb + (size_t)snode[arow] * IN_DIM + aq * 16;
    const unsigned short* bptr = Wt + arow * IN_DIM + aq * 16;

    float    ar[16];
    unsigned bw[8];

#define LOAD_REGS(KK) do {                                           \
        _Pragma("unroll")                                            \
        for (int q = 0; q < 4; q++) {                                \
            const floatx4 v = *(const floatx4*)(aptr + (KK) * 32 + q * 4); \
            ar[q*4+0]=v[0]; ar[q*4+1]=v[1]; ar[q*4+2]=v[2]; ar[q*4+3]=v[3]; \
        }                                                            \
        const uint4 w0 = *(const uint4*)(bptr + (KK) * 32);          \
        const uint4 w1 = *(const uint4*)(bptr + (KK) * 32 + 8);      \
        bw[0]=w0.x; bw[1]=w0.y; bw[2]=w0.z; bw[3]=w0.w;              \
        bw[4]=w1.x; bw[5]=w1.y; bw[6]=w1.z; bw[7]=w1.w;              \
    } while (0)

#define WRITE_LDS() do {                                             \
        uint4 uv0, uv1;                                              \
        uv0.x = cvtpk(ar[0],  ar[1]);  uv0.y = cvtpk(ar[2],  ar[3]); \
        uv0.z = cvtpk(ar[4],  ar[5]);  uv0.w = cvtpk(ar[6],  ar[7]); \
        uv1.x = cvtpk(ar[8],  ar[9]);  uv1.y = cvtpk(ar[10], ar[11]);\
        uv1.z = cvtpk(ar[12], ar[13]); uv1.w = cvtpk(ar[14], ar[15]);\
        *(uint4*)&A_lds[arow * 40 + aq * 16]     = uv0;              \
        *(uint4*)&A_lds[arow * 40 + aq * 16 + 8] = uv1;              \
        uint4 b0, b1;                                                \
        b0.x=bw[0]; b0.y=bw[1]; b0.z=bw[2]; b0.w=bw[3];              \
        b1.x=bw[4]; b1.y=bw[5]; b1.z=bw[6]; b1.w=bw[7];              \
        *(uint4*)&B_lds[arow * 40 + aq * 16]     = b0;               \
        *(uint4*)&B_lds[arow * 40 + aq * 16 + 8] = b1;               \
    } while (0)

    const int wave = tid >> 6, lane = tid & 63;
    const int wr = (wave & 1) * 64;
    const int wc = (wave >> 1) * 64;
    const int fr = lane & 15;
    const int koff = (lane >> 4) * 8;

    floatx4 acc[4][4];
#pragma unroll
    for (int i = 0; i < 4; i++)
#pragma unroll
        for (int j = 0; j < 4; j++) acc[i][j] = (floatx4){0.f, 0.f, 0.f, 0.f};

    LOAD_REGS(0);
    WRITE_LDS();

    for (int kk = 0; kk < 8; ++kk) {
        if (kk < 7) LOAD_REGS(kk + 1);
        __syncthreads();
        short8 af[4], bf[4];
#pragma unroll
        for (int t = 0; t < 4; t++) {
            af[t] = *(const short8*)&A_lds[(wr + t * 16 + fr) * 40 + koff];
            bf[t] = *(const short8*)&B_lds[(wc + t * 16 + fr) * 40 + koff];
        }
#pragma unroll
        for (int rt = 0; rt < 4; rt++)
#pragma unroll
            for (int ct = 0; ct < 4; ct++)
                acc[rt][ct] = __builtin_amdgcn_mfma_f32_16x16x32_bf16(
                    bf[ct], af[rt], acc[rt][ct], 0, 0, 0);
        __syncthreads();
        if (kk < 7) WRITE_LDS();
    }

#pragma unroll
    for (int rt = 0; rt < 4; rt++) {
        int lrow = wr + rt * 16 + fr;
        int grow = m0 + lrow;
        float sc = sscale[lrow];
        if (grow < n) {
#pragma unroll
            for (int ct = 0; ct < 4; ct++) {
                int col = wc + ct * 16 + (lane >> 4) * 4;
                uint2 o;
                o.x = cvtpk(acc[rt][ct][0] * sc, acc[rt][ct][1] * sc);
                o.y = cvtpk(acc[rt][ct][2] * sc, acc[rt][ct][3] * sc);
                *(uint2*)&h[(size_t)grow * OUT_DIM + col] = o;
            }
        }
    }
#undef LOAD_REGS
#undef WRITE_LDS
}

// ---------------------------------------------------------------------------
// Kernel 4: CSR-SpMM + norm + bias. One wave per row; coalesced index load +
// shfl broadcast; 16 outstanding 256B gathers; non-temporal feat stores.
// 256 thr, no LDS -> max occupancy (latency-bound kernel lives on waves).
// ---------------------------------------------------------------------------
__global__ __launch_bounds__(256) void spmm_csr_kernel(
    const int* __restrict__ row_start, const int* __restrict__ boffs,
    const int* __restrict__ csr_src, const unsigned short* __restrict__ h,
    const float* __restrict__ bias, float* __restrict__ out_feat, int n)
{
    const int lane = threadIdx.x & 63;
    const int c2 = lane * 2;
    const int row = blockIdx.x * 4 + (threadIdx.x >> 6);
    if (row >= n) return;

    const int rs = row_start[row]     + boffs[row >> 10];
    const int re = row_start[row + 1] + boffs[(row + 1) >> 10];
    const int deg = re - rs;

    float aL[4] = {0.f, 0.f, 0.f, 0.f};
    float aH[4] = {0.f, 0.f, 0.f, 0.f};

    for (int base = 0; base < deg; base += 64) {
        const int cnt = min(deg - base, 64);
        int idx = (lane < cnt) ? csr_src[rs + base + lane] : 0;
        int t = 0;
        for (; t + 15 < cnt; t += 16) {
            int s[16];
#pragma unroll
            for (int u = 0; u < 16; u++) s[u] = __shfl(idx, t + u, 64);
            unsigned v[16];
#pragma unroll
            for (int u = 0; u < 16; u++)
                v[u] = *(const unsigned*)&h[(size_t)s[u] * OUT_DIM + c2];
#pragma unroll
            for (int u = 0; u < 16; u++) {
                union { unsigned uu; float f; } x, y;
                x.uu = v[u] << 16;
                y.uu = v[u] & 0xffff0000u;
                aL[u & 3] += x.f;
                aH[u & 3] += y.f;
            }
        }
        for (; t + 3 < cnt; t += 4) {
            int s[4];
#pragma unroll
            for (int u = 0; u < 4; u++) s[u] = __shfl(idx, t + u, 64);
            unsigned v[4];
#pragma unroll
            for (int u = 0; u < 4; u++)
                v[u] = *(const unsigned*)&h[(size_t)s[u] * OUT_DIM + c2];
#pragma unroll
            for (int u = 0; u < 4; u++) {
                union { unsigned uu; float f; } x, y;
                x.uu = v[u] << 16;
                y.uu = v[u] & 0xffff0000u;
                aL[u] += x.f;
                aH[u] += y.f;
            }
        }
        for (; t < cnt; ++t) {
            int s0 = __shfl(idx, t, 64);
            unsigned v0 = *(const unsigned*)&h[(size_t)s0 * OUT_DIM + c2];
            union { unsigned uu; float f; } x, y;
            x.uu = v0 << 16;
            y.uu = v0 & 0xffff0000u;
            aL[0] += x.f;
            aH[0] += y.f;
        }
    }

    const float nd = rsqrtf(fmaxf((float)deg, 1.0f));
    const float f0 = ((aL[0] + aL[1]) + (aL[2] + aL[3])) * nd + bias[c2];
    const float f1 = ((aH[0] + aH[1]) + (aH[2] + aH[3])) * nd + bias[c2 + 1];
    union { float f[2]; unsigned long long u; } o;
    o.f[0] = f0; o.f[1] = f1;
    __builtin_nontemporal_store(o.u,
        (unsigned long long*)&out_feat[(size_t)row * OUT_DIM + c2]);
}

// ---------------------------------------------------------------------------
// Kernel 5: logits = F @ mlp_w + mlp_b via MFMA; non-temporal stores.
// ---------------------------------------------------------------------------
__global__ __launch_bounds__(256) void mlp_mfma_kernel(
    const float* __restrict__ F, const float* __restrict__ mlp_w,
    const float* __restrict__ mlp_b, float* __restrict__ out_logits, int n)
{
    __shared__ unsigned short A_lds[48 * 136];
    __shared__ float s_mlpb[48];

    const int tid = threadIdx.x;
    for (int i = tid; i < 48 * 128; i += 256) {
        int cls = i >> 7, k = i & 127;
        A_lds[cls * 136 + k] =
            (cls < N_CLS) ? f2bf(mlp_w[(size_t)k * N_CLS + cls]) : (unsigned short)0;
    }
    if (tid < 48) s_mlpb[tid] = (tid < N_CLS) ? mlp_b[tid] : 0.f;
    __syncthreads();

    const int wave = tid >> 6, lane = tid & 63;
    const int r = lane & 15, koff = (lane >> 4) * 8;
    const int row = blockIdx.x * 64 + wave * 16 + r;
    const int rowc = (row < n) ? row : (n - 1);
    const float* fp = F + (size_t)rowc * OUT_DIM + koff;

    floatx4 acc[3];
#pragma unroll
    for (int ct = 0; ct < 3; ct++) acc[ct] = (floatx4){0.f, 0.f, 0.f, 0.f};

#pragma unroll
    for (int kk = 0; kk < 4; kk++) {
        floatx4 v0 = *(const floatx4*)(fp + kk * 32);
        floatx4 v1 = *(const floatx4*)(fp + kk * 32 + 4);
        union { unsigned u32[4]; short8 v; } bfr;
        bfr.u32[0] = cvtpk(v0[0], v0[1]);
        bfr.u32[1] = cvtpk(v0[2], v0[3]);
        bfr.u32[2] = cvtpk(v1[0], v1[1]);
        bfr.u32[3] = cvtpk(v1[2], v1[3]);
#pragma unroll
        for (int ct = 0; ct < 3; ct++) {
            short8 af = *(const short8*)&A_lds[(ct * 16 + r) * 136 + kk * 32 + koff];
            acc[ct] = __builtin_amdgcn_mfma_f32_16x16x32_bf16(af, bfr.v, acc[ct], 0, 0, 0);
        }
    }

    if (row < n) {
#pragma unroll
        for (int ct = 0; ct < 3; ct++)
#pragma unroll
            for (int i = 0; i < 4; i++) {
                int cls = ct * 16 + (lane >> 4) * 4 + i;
                if (cls < N_CLS)
                    __builtin_nontemporal_store(acc[ct][i] + s_mlpb[cls],
                        &out_logits[(size_t)row * N_CLS + cls]);
            }
    }
}

// ---------------------------------------------------------------------------
extern "C" void kernel_launch(void* const* d_in, const int* in_sizes, int n_in,
                              void* d_out, int out_size, void* d_ws, size_t ws_size,
                              hipStream_t stream) {
    const int*   nodes = (const int*)d_in[0];
    const int*   src   = (const int*)d_in[1];
    const int*   dst   = (const int*)d_in[2];
    const float* emb   = (const float*)d_in[3];
    const float* W     = (const float*)d_in[4];
    const float* b     = (const float*)d_in[5];
    const float* mlp_w = (const float*)d_in[6];
    const float* mlp_b = (const float*)d_in[7];

    const int n  = in_sizes[0];   // 50000
    const int ne = in_sizes[1];   // 800000

    // ws layout (ints): cnt_out[n] | bsum[512] | boffs[512] | done[8] |
    //   row_start[n+8] | csr_src[ne] | partial_out[NE_CH*n] |
    //   partial_in[NE_CH*n] | bf16 Wt | bf16 h[n*128]
    int* cnt_out     = (int*)d_ws;
    int* bsum        = cnt_out + n;
    int* boffs       = bsum + 512;
    int* done        = boffs + 512;
    int* row_start   = done + 8;
    int* csr_src     = row_start + n + 8;
    int* partial_out = csr_src + ne;
    int* partial_in  = partial_out + (size_t)NE_CH * n;
    size_t off = ((size_t)(2 * n + 1048) + (size_t)ne + 2 * (size_t)NE_CH * n) * sizeof(int);
    off = (off + 15) & ~(size_t)15;
    unsigned short* Wt = (unsigned short*)((char*)d_ws + off);
    off += (size_t)IN_DIM * OUT_DIM * sizeof(unsigned short);
    off = (off + 15) & ~(size_t)15;
    unsigned short* h = (unsigned short*)((char*)d_ws + off);

    float* out_feat   = (float*)d_out;                    // n*128
    float* out_logits = out_feat + (size_t)n * OUT_DIM;   // n*40

    const int ns = (n + SLICE - 1) / SLICE;               // 3
    const int chunk = (((ne + NE_CH - 1) / NE_CH) + 3) & ~3;
    const int nbh = ns * NE_CH;                           // 120 hist blocks
    const int nbw = (IN_DIM * OUT_DIM + 255) / 256;       // 128 wconv blocks
    const int nb = (n + 1023) / 1024;                     // 49 scan blocks
    const int ngb = (n + 127) / 128;                      // 391 gemm blocks

    hist_wconv_kernel<<<nbh + nbw, 256, 0, stream>>>(
        src, dst, partial_out, partial_in, W, Wt, done, ne, n, chunk, nbh);
    reduce_scan_kernel<<<nb, 256, 0, stream>>>(
        partial_out, partial_in, cnt_out, row_start, bsum, boffs, done, n);
    scatter_gemm_kernel<<<nbh + ngb, 256, 0, stream>>>(
        src, dst, row_start, boffs, partial_in, csr_src,
        nodes, emb, Wt, cnt_out, h, ne, n, chunk, nbh);
    spmm_csr_kernel<<<(n + 3) / 4, 256, 0, stream>>>(
        row_start, boffs, csr_src, h, b, out_feat, n);
    mlp_mfma_kernel<<<(n + 63) / 64, 256, 0, stream>>>(
        out_feat, mlp_w, mlp_b, out_logits, n);
}